// Round 11
// baseline (151.753 us; speedup 1.0000x reference)
//
#include <hip/hip_runtime.h>
#include <cstdint>

// WealthRNN v11 = v10 with the one assembler fix: lgkmcnt is a 4-bit field
// (max 15) -> mid-batch counted wait LGKMN(16) becomes LGKMN(15). In-order DS
// retirement means <=15 outstanding still proves all 32 next-group ds_reads
// landed (youngest 15 ops are ds_writes); semantics otherwise identical.
//  4 columns/thread, 256-col blocks, 64 blocks.
//  wave0: ring 8 slots x 8KiB, D=7 groups (56 DMA ops in flight, WAITV(48)),
//         32 ds_read prefetch next group, 4x4 exact chain steps, 16 ds_write,
//         LGKM(15) counted, LGKM0+barrier per 4 groups. A/B sets, no copies.
//  wave1: per batch: barrier, vmcnt(16) (2-batch store pipeline), keep-alive,
//         16x ds_read_b128, lgkm0, 16x buffer_store_dwordx4.

#define S_LEN 1024
#define B_LEN 16384
#define NG    255      // 4-step groups, steps 1..1020
#define D     7        // DMA prefetch depth (groups)
#define GSTEP ((size_t)4 * B_LEN)

typedef uint32_t u32x4 __attribute__((ext_vector_type(4)));
typedef float    f32x4 __attribute__((ext_vector_type(4)));

__device__ __forceinline__ u32x4 make_srsrc(const void* p) {
    u32x4 r;
    uint64_t a = (uint64_t)p;
    r.x = (uint32_t)a;
    r.y = (uint32_t)(a >> 32);   // base hi, stride=0
    r.z = 0xFFFFFFFFu;           // bounds check disabled
    r.w = 0x00020000u;           // raw dword descriptor
    return r;
}

#define SBAR0 __builtin_amdgcn_sched_barrier(0)
#define WAITV(N) do { asm volatile("s_waitcnt vmcnt(%0)" :: "n"(N)); SBAR0; } while (0)
#define LGKMN(N) do { asm volatile("s_waitcnt lgkmcnt(%0)" :: "n"(N)); SBAR0; } while (0)

__device__ __forceinline__ void dma16(const float* g, float* l) {
    __builtin_amdgcn_global_load_lds(
        (const __attribute__((address_space(1))) void*)g,
        (__attribute__((address_space(3))) void*)l, 16, 0, 0);
}

__device__ __forceinline__ float step_fn(float h, float x, float r,
                                         float win, float wh,
                                         float c1, float c2, float c3,
                                         float wf1, float wf2) {
    float inv   = __builtin_amdgcn_rcpf(fmaf(h, r, 1.0f)); // 1/(1+h*r)
    float h_adj = fmaf(h, r, h) * inv;                      // h*(1+r)/(1+h*r)
    float ingate = fmaf(wh, h_adj, fmaf(x, win, c1));
    float t  = fmaxf(ingate, 0.0f);
    float g2 = fmaf(wf1, t, c2);
    float t2 = fmaxf(g2, 0.0f);
    return fmaf(wf2, t2, c3);
}

#define DSR(OFF, DST) \
    asm volatile("ds_read_b32 %0, %1 offset:" #OFF : "=v"(DST) : "v"(ra_))
#define DSW(OFF, V) \
    asm volatile("ds_write_b32 %0, %1 offset:" #OFF :: "v"(wa_), "v"(V))

// prefetch one group tile: x[p][k] @ p*1024+k*256 B, r[p][k] @ 4096+p*1024+k*256 B
#define PREF32(TX, TR) do { \
    DSR(0,    TX[0][0]); DSR(256,  TX[0][1]); DSR(512,  TX[0][2]); DSR(768,  TX[0][3]); \
    DSR(1024, TX[1][0]); DSR(1280, TX[1][1]); DSR(1536, TX[1][2]); DSR(1792, TX[1][3]); \
    DSR(2048, TX[2][0]); DSR(2304, TX[2][1]); DSR(2560, TX[2][2]); DSR(2816, TX[2][3]); \
    DSR(3072, TX[3][0]); DSR(3328, TX[3][1]); DSR(3584, TX[3][2]); DSR(3840, TX[3][3]); \
    DSR(4096, TR[0][0]); DSR(4352, TR[0][1]); DSR(4608, TR[0][2]); DSR(4864, TR[0][3]); \
    DSR(5120, TR[1][0]); DSR(5376, TR[1][1]); DSR(5632, TR[1][2]); DSR(5888, TR[1][3]); \
    DSR(6144, TR[2][0]); DSR(6400, TR[2][1]); DSR(6656, TR[2][2]); DSR(6912, TR[2][3]); \
    DSR(7168, TR[3][0]); DSR(7424, TR[3][1]); DSR(7680, TR[3][2]); DSR(7936, TR[3][3]); \
} while (0)

#define STEPP(P, K) h##P = step_fn(h##P, CXl[P][K], CRl[P][K], win, wh, c1, c2, c3, wf1, wf2)

// compute 4 steps x 4 panels of one group; write outb slot tile [4][256]
#define COMPUTE16(CXa, CRa) do { \
    float (*CXl)[4] = (CXa); \
    float (*CRl)[4] = (CRa); \
    STEPP(0,0); DSW(0,    h0); STEPP(1,0); DSW(256,  h1); \
    STEPP(2,0); DSW(512,  h2); STEPP(3,0); DSW(768,  h3); \
    STEPP(0,1); DSW(1024, h0); STEPP(1,1); DSW(1280, h1); \
    STEPP(2,1); DSW(1536, h2); STEPP(3,1); DSW(1792, h3); \
    STEPP(0,2); DSW(2048, h0); STEPP(1,2); DSW(2304, h1); \
    STEPP(2,2); DSW(2560, h2); STEPP(3,2); DSW(2816, h3); \
    STEPP(0,3); DSW(3072, h0); STEPP(1,3); DSW(3328, h1); \
    STEPP(2,3); DSW(3584, h2); STEPP(3,3); DSW(3840, h3); \
} while (0)

// one group: optional {DMA(g+D); WAITV(48)}; prefetch g+1 -> (NX,NR);
// compute g from (CX,CR); counted LGKM or batch-end publish.
#define GBODY(g_, CX, CR, NX, NR, DODMA_, ENDB_) do { \
    if (DODMA_) { \
        float* lb_ = &ringf[(size_t)(((g_) + D) & 7) * 2048]; \
        dma16(gx,       lb_ + 0);    dma16(gx + 64,  lb_ + 256); \
        dma16(gx + 128, lb_ + 512);  dma16(gx + 192, lb_ + 768); \
        dma16(gr,       lb_ + 1024); dma16(gr + 64,  lb_ + 1280); \
        dma16(gr + 128, lb_ + 1536); dma16(gr + 192, lb_ + 1792); \
        gx += GSTEP; gr += GSTEP; \
        WAITV(48); \
    } \
    { uint32_t ra_ = rbase + (uint32_t)((((g_) + 1) & 7) * 8192); PREF32(NX, NR); } \
    { uint32_t wa_ = wbase + (uint32_t)(((g_) & 7) * 4096); COMPUTE16(CX, CR); } \
    if (ENDB_) { LGKMN(0); __builtin_amdgcn_s_barrier(); } else { LGKMN(15); } \
} while (0)

// wave1 helpers
#define ST4(SA, SB, SC, SD) \
    asm volatile("buffer_store_dwordx4 %0, %1, %2, %3 offen" :: "v"(SA), "v"(vo0), "s"(ro), "s"(so_)); \
    asm volatile("buffer_store_dwordx4 %0, %1, %2, %3 offen" :: "v"(SB), "v"(vo1), "s"(ro), "s"(so_)); \
    asm volatile("buffer_store_dwordx4 %0, %1, %2, %3 offen" :: "v"(SC), "v"(vo2), "s"(ro), "s"(so_)); \
    asm volatile("buffer_store_dwordx4 %0, %1, %2, %3 offen" :: "v"(SD), "v"(vo3), "s"(ro), "s"(so_))

#define WDR(OFF, DST) \
    asm volatile("ds_read_b128 %0, %1 offset:" #OFF : "=v"(DST) : "v"(a_))

#define WBATCH(SO0_, LOFF_, S0,S1,S2,S3,S4,S5,S6,S7,S8,S9,S10,S11,S12,S13,S14,S15) do { \
    __builtin_amdgcn_s_barrier(); \
    asm volatile("s_waitcnt vmcnt(16)"); SBAR0; \
    asm volatile("" :: "v"(S0),"v"(S1),"v"(S2),"v"(S3),"v"(S4),"v"(S5),"v"(S6),"v"(S7), \
                       "v"(S8),"v"(S9),"v"(S10),"v"(S11),"v"(S12),"v"(S13),"v"(S14),"v"(S15)); \
    { uint32_t a_ = oa + (LOFF_); \
      WDR(0,S0); WDR(1024,S1); WDR(2048,S2); WDR(3072,S3); \
      WDR(4096,S4); WDR(5120,S5); WDR(6144,S6); WDR(7168,S7); \
      WDR(8192,S8); WDR(9216,S9); WDR(10240,S10); WDR(11264,S11); \
      WDR(12288,S12); WDR(13312,S13); WDR(14336,S14); WDR(15360,S15); } \
    LGKMN(0); \
    { uint32_t so_ = (SO0_); \
      ST4(S0,S1,S2,S3);   so_ += (4u << 16); \
      ST4(S4,S5,S6,S7);   so_ += (4u << 16); \
      ST4(S8,S9,S10,S11); so_ += (4u << 16); \
      ST4(S12,S13,S14,S15); } \
} while (0)

__global__ __launch_bounds__(128) void wealth_rnn_kernel(
    const float* __restrict__ inputs,    // [S, B]
    const float* __restrict__ returns,   // [S-1, B]
    const float* __restrict__ target,
    const float* __restrict__ w_in_p,
    const float* __restrict__ w_h_p,
    const float* __restrict__ b_h_p,
    const float* __restrict__ w_fc1_p,
    const float* __restrict__ w_fc2_p,
    float* __restrict__ out)             // [S*B] then [B] hT
{
    __shared__ float ringf[8 * 2048];    // 64 KiB: 8 slots x {x[4p][4k][64], r[4p][4k][64]}
    __shared__ float outbf[8192];        // 32 KiB: 8 slots x [4k][256]

    const int tid  = threadIdx.x;
    const int lane = tid & 63;
    const int wid  = tid >> 6;
    const int b0   = blockIdx.x * 256;

    if (wid == 0) {
        // ===================== producer / compute wave ======================
        const float pi_bar = target[0];
        const float win = w_in_p[0];
        const float wh  = w_h_p[0];
        const float bh  = b_h_p[0];
        const float wf1 = w_fc1_p[0];
        const float wf2 = w_fc2_p[0];
        const float c1 = bh - pi_bar;
        const float c2 = 2.0f * bh;
        const float c3 = pi_bar + bh;

        // 4 columns per lane: col_p = b0 + p*64 + lane
        float h0 = inputs[b0 + 0 * 64 + lane];
        float h1 = inputs[b0 + 1 * 64 + lane];
        float h2 = inputs[b0 + 2 * 64 + lane];
        float h3 = inputs[b0 + 3 * 64 + lane];

        u32x4 ro = make_srsrc(out);
        const uint32_t voff = (uint32_t)((b0 + lane) * 4);
        const uint32_t so0 = 0u;
        asm volatile("buffer_store_dword %0, %1, %2, %3 offen"            :: "v"(h0), "v"(voff), "s"(ro), "s"(so0));
        asm volatile("buffer_store_dword %0, %1, %2, %3 offen offset:256" :: "v"(h1), "v"(voff), "s"(ro), "s"(so0));
        asm volatile("buffer_store_dword %0, %1, %2, %3 offen offset:512" :: "v"(h2), "v"(voff), "s"(ro), "s"(so0));
        asm volatile("buffer_store_dword %0, %1, %2, %3 offen offset:768" :: "v"(h3), "v"(voff), "s"(ro), "s"(so0));

        const int lr = lane >> 4;
        const int lc = (lane & 15) * 4;
        const float* gx = inputs  + (size_t)(1 + lr) * B_LEN + b0 + lc;
        const float* gr = returns + (size_t)lr       * B_LEN + b0 + lc;

        asm volatile("" ::: "memory");  // pin entry mem-ops above counted region

        // prologue: DMA groups 0..D-1 (7 groups x 8 ops = 56; +4 entry = 60)
#pragma unroll
        for (int j = 0; j < D; ++j) {
            float* lb_ = &ringf[(size_t)j * 2048];
            dma16(gx,       lb_ + 0);    dma16(gx + 64,  lb_ + 256);
            dma16(gx + 128, lb_ + 512);  dma16(gx + 192, lb_ + 768);
            dma16(gr,       lb_ + 1024); dma16(gr + 64,  lb_ + 1280);
            dma16(gr + 128, lb_ + 1536); dma16(gr + 192, lb_ + 1792);
            gx += GSTEP; gr += GSTEP;
        }

        const uint32_t rbase = (uint32_t)(uintptr_t)&ringf[0] + (uint32_t)lane * 4u;
        const uint32_t wbase = (uint32_t)(uintptr_t)&outbf[0] + (uint32_t)lane * 4u;

        float xA[4][4], rA[4][4], xB[4][4], rB[4][4];

        WAITV(48);                        // retire entry(4) + group 0 -> ready
        { uint32_t ra_ = rbase; PREF32(xA, rA); }
        LGKMN(0);

        // main: quads q = 0,4,...,244 (groups 0..247, DMA thru group 254)
        for (int q = 0; q < 248; q += 4) {
            GBODY(q + 0, xA, rA, xB, rB, 1, 0);
            GBODY(q + 1, xB, rB, xA, rA, 1, 0);
            GBODY(q + 2, xA, rA, xB, rB, 1, 0);
            GBODY(q + 3, xB, rB, xA, rA, 1, 1);
        }

        // drain: all DMAs issued; groups 248..253, then final 254
        WAITV(0);
        GBODY(248, xA, rA, xB, rB, 0, 0);
        GBODY(249, xB, rB, xA, rA, 0, 0);
        GBODY(250, xA, rA, xB, rB, 0, 0);
        GBODY(251, xB, rB, xA, rA, 0, 1);
        GBODY(252, xA, rA, xB, rB, 0, 0);
        GBODY(253, xB, rB, xA, rA, 0, 0);
        {   // g = 254 (slot 6), uses A, no prefetch; publish partial batch
            uint32_t wa_ = wbase + (uint32_t)((254 & 7) * 4096);
            COMPUTE16(xA, rA);
            LGKMN(0);
            __builtin_amdgcn_s_barrier();
        }

        asm volatile("" ::: "memory");  // keep tail mem-ops below counted region

        // tail steps 1021..1023 + hT (plain; pipeline fully drained)
#pragma unroll
        for (int s = 4 * NG + 1; s < S_LEN; ++s) {
#pragma unroll
            for (int p = 0; p < 4; ++p) {
                const int col = b0 + p * 64 + lane;
                const float x = inputs[(size_t)s * B_LEN + col];
                const float r = returns[(size_t)(s - 1) * B_LEN + col];
                float* hp = (p == 0) ? &h0 : (p == 1) ? &h1 : (p == 2) ? &h2 : &h3;
                *hp = step_fn(*hp, x, r, win, wh, c1, c2, c3, wf1, wf2);
                out[(size_t)s * B_LEN + col] = *hp;
            }
        }
#pragma unroll
        for (int p = 0; p < 4; ++p) {
            const int col = b0 + p * 64 + lane;
            const float hv = (p == 0) ? h0 : (p == 1) ? h1 : (p == 2) ? h2 : h3;
            out[(size_t)S_LEN * B_LEN + col] = hv;
        }
    } else {
        // ============== consumer / store wave (batch pipelined) =============
        const int j = lane;
        u32x4 ro = make_srsrc(out);
        const uint32_t vob = (uint32_t)((b0 + j * 4) * 4);
        const uint32_t vo0 = vob;
        const uint32_t vo1 = vob + 65536u;    // +1 output row (B_LEN*4 bytes)
        const uint32_t vo2 = vob + 131072u;   // +2 rows
        const uint32_t vo3 = vob + 196608u;   // +3 rows
        const uint32_t oa = (uint32_t)(uintptr_t)&outbf[0] + (uint32_t)j * 16u;

        f32x4 s0={0,0,0,0},s1={0,0,0,0},s2={0,0,0,0},s3={0,0,0,0},
              s4={0,0,0,0},s5={0,0,0,0},s6={0,0,0,0},s7={0,0,0,0},
              s8={0,0,0,0},s9={0,0,0,0},s10={0,0,0,0},s11={0,0,0,0},
              s12={0,0,0,0},s13={0,0,0,0},s14={0,0,0,0},s15={0,0,0,0};
        f32x4 t0={0,0,0,0},t1={0,0,0,0},t2={0,0,0,0},t3={0,0,0,0},
              t4={0,0,0,0},t5={0,0,0,0},t6={0,0,0,0},t7={0,0,0,0},
              t8={0,0,0,0},t9={0,0,0,0},t10={0,0,0,0},t11={0,0,0,0},
              t12={0,0,0,0},t13={0,0,0,0},t14={0,0,0,0},t15={0,0,0,0};

        // full batches bt = 0..62 (groups 0..251); batch bt rows 16bt+1..+16
        for (int bt2 = 0; bt2 < 31; ++bt2) {
            WBATCH(((uint32_t)(32 * bt2 + 1)) << 16, 0,
                   s0,s1,s2,s3,s4,s5,s6,s7,s8,s9,s10,s11,s12,s13,s14,s15);
            WBATCH(((uint32_t)(32 * bt2 + 17)) << 16, 16384,
                   t0,t1,t2,t3,t4,t5,t6,t7,t8,t9,t10,t11,t12,t13,t14,t15);
        }
        WBATCH(((uint32_t)(16 * 62 + 1)) << 16, 0,
               s0,s1,s2,s3,s4,s5,s6,s7,s8,s9,s10,s11,s12,s13,s14,s15);

        // partial batch 63: groups 252..254 (12 rows 1009..1020), LDS half 1
        __builtin_amdgcn_s_barrier();
        asm volatile("s_waitcnt vmcnt(16)"); SBAR0;
        asm volatile("" :: "v"(t0),"v"(t1),"v"(t2),"v"(t3),"v"(t4),"v"(t5),
                           "v"(t6),"v"(t7),"v"(t8),"v"(t9),"v"(t10),"v"(t11));
        {
            uint32_t a_ = oa + 16384;
            WDR(0,t0); WDR(1024,t1); WDR(2048,t2); WDR(3072,t3);
            WDR(4096,t4); WDR(5120,t5); WDR(6144,t6); WDR(7168,t7);
            WDR(8192,t8); WDR(9216,t9); WDR(10240,t10); WDR(11264,t11);
        }
        LGKMN(0);
        {
            uint32_t so_ = ((uint32_t)(4 * 252 + 1)) << 16;
            ST4(t0,t1,t2,t3);   so_ += (4u << 16);
            ST4(t4,t5,t6,t7);   so_ += (4u << 16);
            ST4(t8,t9,t10,t11);
        }
    }
}

extern "C" void kernel_launch(void* const* d_in, const int* in_sizes, int n_in,
                              void* d_out, int out_size, void* d_ws, size_t ws_size,
                              hipStream_t stream) {
    const float* inputs  = (const float*)d_in[0];
    const float* returns = (const float*)d_in[1];
    const float* target  = (const float*)d_in[2];
    const float* w_in    = (const float*)d_in[3];
    const float* w_h     = (const float*)d_in[4];
    const float* b_h     = (const float*)d_in[5];
    const float* w_fc1   = (const float*)d_in[6];
    const float* w_fc2   = (const float*)d_in[7];
    float* out = (float*)d_out;

    dim3 grid(B_LEN / 256);
    dim3 block(128);
    hipLaunchKernelGGL(wealth_rnn_kernel, grid, block, 0, stream,
                       inputs, returns, target, w_in, w_h, b_h, w_fc1, w_fc2, out);
}

// Round 12
// 45.607 us; speedup vs baseline: 3.3274x; 3.3274x over previous
//
#include <hip/hip_runtime.h>
#include <cstdint>

// WealthRNN v13: 256 blocks x {wave0 compute, wave1 DMA+stores}.
// Diagnosis (v11): asm volatile between steps = LLVM scheduling boundary ->
// no ILP, ~6cy/instr. Fix: hot path pure C++ (v8's verified 5-hop chain,
// 25cy/step, off-chain coeffs fill gaps); LDS asm only at group boundaries
// (ds_read2_b32 x4 prefetch, ds_write2_b32 x2 writeback, counted lgkmcnt).
// Wave0 issues ZERO vmem; wave1 owns DMA (global_load_lds) + output stores
// with hand-audited mixed vmcnt (table below). Barrier per 4-group batch.
//
// wave1 per-iter vmcnt table (I_bt = dma ops issued at iter bt):
//   I: 8 (bt<=59), 6 (bt=60), 0 (bt>=61)
//   pre (protect stores bt-2):  bt 2..59:20, 60:18, 61:10, 62:4, 63:4
//   end (ring thru b(bt+2)g0):  bt 0:18, 1..59:22, 60:20, 61:12, 62:8(all)

#define S_LEN 1024
#define B_LEN 16384
#define NG    255
#define GSTEP ((size_t)4 * B_LEN)

typedef uint32_t u32x4 __attribute__((ext_vector_type(4)));
typedef float    f32x4 __attribute__((ext_vector_type(4)));
typedef float    f32x2 __attribute__((ext_vector_type(2)));

__device__ __forceinline__ u32x4 make_srsrc(const void* p) {
    u32x4 r;
    uint64_t a = (uint64_t)p;
    r.x = (uint32_t)a;
    r.y = (uint32_t)(a >> 32);
    r.z = 0xFFFFFFFFu;
    r.w = 0x00020000u;
    return r;
}

#define SBAR0 __builtin_amdgcn_sched_barrier(0)
#define WAITV(N) do { asm volatile("s_waitcnt vmcnt(%0)" :: "n"(N)); SBAR0; } while (0)
#define LGKMN(N) do { asm volatile("s_waitcnt lgkmcnt(%0)" :: "n"(N)); SBAR0; } while (0)

__device__ __forceinline__ void dma16(const float* g, float* l) {
    __builtin_amdgcn_global_load_lds(
        (const __attribute__((address_space(1))) void*)g,
        (__attribute__((address_space(3))) void*)l, 16, 0, 0);
}

// exact step (tail only)
__device__ __forceinline__ float step_fn(float h, float x, float r,
                                         float win, float wh,
                                         float c1, float c2, float c3,
                                         float wf1, float wf2) {
    float inv   = __builtin_amdgcn_rcpf(fmaf(h, r, 1.0f));
    float h_adj = fmaf(h, r, h) * inv;
    float ingate = fmaf(wh, h_adj, fmaf(x, win, c1));
    float t  = fmaxf(ingate, 0.0f);
    float g2 = fmaf(wf1, t, c2);
    float t2 = fmaxf(g2, 0.0f);
    return fmaf(wf2, t2, c3);
}

// v8's verified re-rooted chain: state st = t2 (post-ReLU), h = wf2*st+c3.
// 1/(1+u) ~ (1-u)(1+u^2), |u|<=~0.06 -> err <= 4e-5 (passed R8, absmax 0.0).
struct Consts {
    float winwf1, whwf1, c1wf1c2, c2p, wf2, c3;
};

template<bool POS>
__device__ __forceinline__ void step_fast(float& st, float& hv,
                                          float x, float r, const Consts& C) {
    float A1 = C.wf2 * r;                    // off-chain
    float B1 = C.c3 * r;
    float w  = fmaf(C.whwf1, r, C.whwf1);
    float A2 = C.wf2 * w;
    float B2 = C.c3 * w;
    float KK = fmaf(x, C.winwf1, C.c1wf1c2);
    float u  = fmaf(A1, st, B1);             // chain hop 1
    float M  = fmaf(A2, st, B2);             // parallel hop 1
    float q  = fmaf(u, u, 1.0f);             // hop 2
    float om = 1.0f - u;                     // parallel hop 2
    float p  = om * q;                       // hop 3
    float Aa = fmaf(M, p, KK);               // hop 4
    if (POS) st = fmaxf(Aa, C.c2p);          // hop 5
    else     st = fminf(fmaxf(Aa, 0.0f), C.c2p);
    hv = fmaf(C.wf2, st, C.c3);              // off-chain
}

template<bool POS>
__device__ __forceinline__ void step_first(float& st, float& hv,
                                           float x, float r, float h0,
                                           const Consts& C) {
    float w  = fmaf(C.whwf1, r, C.whwf1);
    float KK = fmaf(x, C.winwf1, C.c1wf1c2);
    float u  = h0 * r;
    float M  = w * h0;
    float q  = fmaf(u, u, 1.0f);
    float om = 1.0f - u;
    float p  = om * q;
    float Aa = fmaf(M, p, KK);
    if (POS) st = fmaxf(Aa, C.c2p);
    else     st = fminf(fmaxf(Aa, 0.0f), C.c2p);
    hv = fmaf(C.wf2, st, C.c3);
}

// ring: 16 slots x 512 floats {x[4][64], r[4][64]}; read next group g1
#define RD_GROUP(g1, X01, X23, R01, R23) do { \
    uint32_t ax_ = rbase + (uint32_t)(((g1) & 15) * 2048); \
    uint32_t ar_ = ax_ + 1024u; \
    asm volatile("ds_read2_b32 %0, %1 offset0:0 offset1:64"    : "=v"(X01) : "v"(ax_)); \
    asm volatile("ds_read2_b32 %0, %1 offset0:128 offset1:192" : "=v"(X23) : "v"(ax_)); \
    asm volatile("ds_read2_b32 %0, %1 offset0:0 offset1:64"    : "=v"(R01) : "v"(ar_)); \
    asm volatile("ds_read2_b32 %0, %1 offset0:128 offset1:192" : "=v"(R23) : "v"(ar_)); \
} while (0)

#define WR_GROUP(g_, H0, H1, H2, H3) do { \
    uint32_t wa_ = wbase + (uint32_t)(((g_) & 7) * 1024); \
    asm volatile("ds_write2_b32 %0, %1, %2 offset0:0 offset1:64"    :: "v"(wa_), "v"(H0), "v"(H1)); \
    asm volatile("ds_write2_b32 %0, %1, %2 offset0:128 offset1:192" :: "v"(wa_), "v"(H2), "v"(H3)); \
} while (0)

#define STEPS4(X01, X23, R01, R23) do { \
    step_fast<POS>(st, hv0, (X01).x, (R01).x, C); \
    step_fast<POS>(st, hv1, (X01).y, (R01).y, C); \
    step_fast<POS>(st, hv2, (X23).x, (R23).x, C); \
    step_fast<POS>(st, hv3, (X23).y, (R23).y, C); \
} while (0)

template<bool POS>
__device__ __forceinline__ void wave0_impl(
    const float* inputs, const float* returns,
    float pi_bar, float win, float wh, float bh, float wf1, float wf2,
    float* out, int b0, int lane, float* ringp, float* outbp)
{
    const int b = b0 + lane;
    const float c1 = bh - pi_bar;
    const float c2 = 2.0f * bh;
    const float c3 = pi_bar + bh;
    Consts C;
    C.winwf1  = win * wf1;
    C.whwf1   = wh * wf1;
    C.c1wf1c2 = fmaf(c1, wf1, c2);
    C.c2p     = fmaxf(c2, 0.0f);
    C.wf2     = wf2;
    C.c3      = c3;

    const float h0v = inputs[b];
    out[b] = h0v;                               // row 0 (C++; pre-region)

    const uint32_t rbase = (uint32_t)(uintptr_t)ringp + (uint32_t)lane * 4u;
    const uint32_t wbase = (uint32_t)(uintptr_t)outbp + (uint32_t)lane * 4u;

    asm volatile("" ::: "memory");              // pin prologue mem-ops above
    __builtin_amdgcn_s_barrier();               // #0: ring groups 0..4 ready

    f32x2 xA01, xA23, rA01, rA23, xB01, xB23, rB01, rB23;
    float st = 0.0f, hv0, hv1, hv2, hv3;

    RD_GROUP(0, xA01, xA23, rA01, rA23);
    LGKMN(0);

    for (int bt = 0; bt < 63; ++bt) {
        const int g0 = 4 * bt;
        // p0 (cur A, read g0+1 -> B)
        RD_GROUP(g0 + 1, xB01, xB23, rB01, rB23);
        LGKMN(4);
        if (bt == 0) {
            step_first<POS>(st, hv0, xA01.x, rA01.x, h0v, C);
        } else {
            step_fast<POS>(st, hv0, xA01.x, rA01.x, C);
        }
        step_fast<POS>(st, hv1, xA01.y, rA01.y, C);
        step_fast<POS>(st, hv2, xA23.x, rA23.x, C);
        step_fast<POS>(st, hv3, xA23.y, rA23.y, C);
        WR_GROUP(g0, hv0, hv1, hv2, hv3);
        // p1 (cur B, read g0+2 -> A)
        RD_GROUP(g0 + 2, xA01, xA23, rA01, rA23);
        LGKMN(6);
        STEPS4(xB01, xB23, rB01, rB23);
        WR_GROUP(g0 + 1, hv0, hv1, hv2, hv3);
        // p2 (cur A, read g0+3 -> B)
        RD_GROUP(g0 + 3, xB01, xB23, rB01, rB23);
        LGKMN(6);
        STEPS4(xA01, xA23, rA01, rA23);
        WR_GROUP(g0 + 2, hv0, hv1, hv2, hv3);
        // p3 (cur B; read g0+4 AFTER writes; publish)
        LGKMN(2);
        STEPS4(xB01, xB23, rB01, rB23);
        WR_GROUP(g0 + 3, hv0, hv1, hv2, hv3);
        RD_GROUP(g0 + 4, xA01, xA23, rA01, rA23);
        LGKMN(4);                                // writes drained; 4 reads float
        __builtin_amdgcn_s_barrier();
    }
    // batch 63: groups 252(A), 253(B), 254(A)
    RD_GROUP(253, xB01, xB23, rB01, rB23);
    LGKMN(4);
    STEPS4(xA01, xA23, rA01, rA23);
    WR_GROUP(252, hv0, hv1, hv2, hv3);
    RD_GROUP(254, xA01, xA23, rA01, rA23);
    LGKMN(6);
    STEPS4(xB01, xB23, rB01, rB23);
    WR_GROUP(253, hv0, hv1, hv2, hv3);
    LGKMN(2);
    STEPS4(xA01, xA23, rA01, rA23);
    WR_GROUP(254, hv0, hv1, hv2, hv3);
    LGKMN(0);
    __builtin_amdgcn_s_barrier();

    asm volatile("" ::: "memory");              // keep tail mem-ops below

    // tail steps 1021..1023 + hT (exact)
    float h = hv3;                               // h_1020
#pragma unroll
    for (int s = 4 * NG + 1; s < S_LEN; ++s) {
        const float x = inputs[(size_t)s * B_LEN + b];
        const float r = returns[(size_t)(s - 1) * B_LEN + b];
        h = step_fn(h, x, r, win, wh, c1, c2, c3, wf1, wf2);
        out[(size_t)s * B_LEN + b] = h;
    }
    out[(size_t)S_LEN * B_LEN + b] = h;
}

// wave1: one iteration. NDMA_ in groups (2 ops each).
#define W1_ITER(bt_, NDMA_, PRE_EN_, PRE_N_, O0, O1, O2, O3, END_EN_, END_N_) do { \
    for (int gi_ = 0; gi_ < (NDMA_); ++gi_) { \
        float* lb_ = &ringf[(size_t)(dmag & 15) * 512]; \
        dma16(gxw, lb_); dma16(grw, lb_ + 256); \
        gxw += GSTEP; grw += GSTEP; ++dmag; \
    } \
    if (PRE_EN_) { \
        asm volatile("s_waitcnt vmcnt(%0)" :: "n"(PRE_N_)); SBAR0; \
        asm volatile("" :: "v"(O0), "v"(O1), "v"(O2), "v"(O3)); \
    } \
    __builtin_amdgcn_s_barrier(); \
    { uint32_t a_ = oa + (uint32_t)(((bt_) & 1) * 4096); \
      asm volatile("ds_read_b128 %0, %1 offset:0"    : "=v"(O0) : "v"(a_)); \
      asm volatile("ds_read_b128 %0, %1 offset:1024" : "=v"(O1) : "v"(a_)); \
      asm volatile("ds_read_b128 %0, %1 offset:2048" : "=v"(O2) : "v"(a_)); \
      asm volatile("ds_read_b128 %0, %1 offset:3072" : "=v"(O3) : "v"(a_)); } \
    LGKMN(0); \
    { uint32_t so_ = ((uint32_t)(16 * (bt_) + 1)) << 16; \
      asm volatile("buffer_store_dwordx4 %0, %1, %2, %3 offen" :: "v"(O0), "v"(vo), "s"(ro), "s"(so_)); \
      so_ += (4u << 16); \
      asm volatile("buffer_store_dwordx4 %0, %1, %2, %3 offen" :: "v"(O1), "v"(vo), "s"(ro), "s"(so_)); \
      so_ += (4u << 16); \
      asm volatile("buffer_store_dwordx4 %0, %1, %2, %3 offen" :: "v"(O2), "v"(vo), "s"(ro), "s"(so_)); \
      so_ += (4u << 16); \
      asm volatile("buffer_store_dwordx4 %0, %1, %2, %3 offen" :: "v"(O3), "v"(vo), "s"(ro), "s"(so_)); } \
    if (END_EN_) { asm volatile("s_waitcnt vmcnt(%0)" :: "n"(END_N_)); SBAR0; } \
} while (0)

__global__ __launch_bounds__(128) void wealth_rnn_kernel(
    const float* __restrict__ inputs,    // [S, B]
    const float* __restrict__ returns,   // [S-1, B]
    const float* __restrict__ target,
    const float* __restrict__ w_in_p,
    const float* __restrict__ w_h_p,
    const float* __restrict__ b_h_p,
    const float* __restrict__ w_fc1_p,
    const float* __restrict__ w_fc2_p,
    float* __restrict__ out)             // [S*B] then [B] hT
{
    __shared__ float ringf[16 * 512];    // 32 KiB input ring, 16 groups
    __shared__ float outbf[8 * 256];     // 8 KiB output, 8 group slots

    const int tid  = threadIdx.x;
    const int lane = tid & 63;
    const int wid  = tid >> 6;
    const int b0   = blockIdx.x * 64;

    if (wid == 0) {
        const float pi_bar = target[0];
        const float win = w_in_p[0];
        const float wh  = w_h_p[0];
        const float bh  = b_h_p[0];
        const float wf1 = w_fc1_p[0];
        const float wf2 = w_fc2_p[0];
        if (wf1 >= 0.0f)
            wave0_impl<true >(inputs, returns, pi_bar, win, wh, bh, wf1, wf2,
                              out, b0, lane, &ringf[0], &outbf[0]);
        else
            wave0_impl<false>(inputs, returns, pi_bar, win, wh, bh, wf1, wf2,
                              out, b0, lane, &ringf[0], &outbf[0]);
    } else {
        // =================== DMA + store wave ===============================
        const int j = lane;
        u32x4 ro = make_srsrc(out);
        const uint32_t vo = (uint32_t)((((j >> 4) * B_LEN) + b0 + (j & 15) * 4) * 4);
        const uint32_t oa = (uint32_t)(uintptr_t)&outbf[0]
                            + (uint32_t)((j >> 4) * 256 + (j & 15) * 16);

        const int lr = j >> 4;
        const int lc = (j & 15) * 4;
        const float* gxw = inputs  + (size_t)(1 + lr) * B_LEN + b0 + lc;
        const float* grw = returns + (size_t)lr       * B_LEN + b0 + lc;
        int dmag = 0;

        // prologue: dma groups 0..11 (batches 0..2, 24 ops)
        for (int gi = 0; gi < 12; ++gi) {
            float* lb_ = &ringf[(size_t)(dmag & 15) * 512];
            dma16(gxw, lb_); dma16(grw, lb_ + 256);
            gxw += GSTEP; grw += GSTEP; ++dmag;
        }
        WAITV(14);                        // ring ready thru b1 g0 (groups 0..4)
        __builtin_amdgcn_s_barrier();     // #0

        f32x4 a0 = {0,0,0,0}, a1 = {0,0,0,0}, a2 = {0,0,0,0}, a3 = {0,0,0,0};
        f32x4 e0 = {0,0,0,0}, e1 = {0,0,0,0}, e2 = {0,0,0,0}, e3 = {0,0,0,0};

        W1_ITER(0, 4, 0, 0,  a0, a1, a2, a3, 1, 18);
        W1_ITER(1, 4, 0, 0,  e0, e1, e2, e3, 1, 22);
        for (int bt = 2; bt <= 58; bt += 2) {
            W1_ITER(bt,     4, 1, 20, a0, a1, a2, a3, 1, 22);
            W1_ITER(bt + 1, 4, 1, 20, e0, e1, e2, e3, 1, 22);
        }
        // bt=58,59 done by loop (58 even). Peel 60..62:
        W1_ITER(60, 3, 1, 18, a0, a1, a2, a3, 1, 20);
        W1_ITER(61, 0, 1, 10, e0, e1, e2, e3, 1, 12);
        W1_ITER(62, 0, 1,  4, a0, a1, a2, a3, 1,  8);
        // partial iter 63: groups 252..254 (rows 1009..1020)
        WAITV(4); SBAR0;
        asm volatile("" :: "v"(e0), "v"(e1), "v"(e2));
        __builtin_amdgcn_s_barrier();
        {
            uint32_t a_ = oa + 4096u;     // half 1
            asm volatile("ds_read_b128 %0, %1 offset:0"    : "=v"(e0) : "v"(a_));
            asm volatile("ds_read_b128 %0, %1 offset:1024" : "=v"(e1) : "v"(a_));
            asm volatile("ds_read_b128 %0, %1 offset:2048" : "=v"(e2) : "v"(a_));
        }
        LGKMN(0);
        {
            uint32_t so_ = ((uint32_t)(16 * 63 + 1)) << 16;
            asm volatile("buffer_store_dwordx4 %0, %1, %2, %3 offen" :: "v"(e0), "v"(vo), "s"(ro), "s"(so_));
            so_ += (4u << 16);
            asm volatile("buffer_store_dwordx4 %0, %1, %2, %3 offen" :: "v"(e1), "v"(vo), "s"(ro), "s"(so_));
            so_ += (4u << 16);
            asm volatile("buffer_store_dwordx4 %0, %1, %2, %3 offen" :: "v"(e2), "v"(vo), "s"(ro), "s"(so_));
        }
    }
}

extern "C" void kernel_launch(void* const* d_in, const int* in_sizes, int n_in,
                              void* d_out, int out_size, void* d_ws, size_t ws_size,
                              hipStream_t stream) {
    const float* inputs  = (const float*)d_in[0];
    const float* returns = (const float*)d_in[1];
    const float* target  = (const float*)d_in[2];
    const float* w_in    = (const float*)d_in[3];
    const float* w_h     = (const float*)d_in[4];
    const float* b_h     = (const float*)d_in[5];
    const float* w_fc1   = (const float*)d_in[6];
    const float* w_fc2   = (const float*)d_in[7];
    float* out = (float*)d_out;

    dim3 grid(B_LEN / 64);
    dim3 block(128);
    hipLaunchKernelGGL(wealth_rnn_kernel, grid, block, 0, stream,
                       inputs, returns, target, w_in, w_h, b_h, w_fc1, w_fc2, out);
}

// Round 13
// 43.687 us; speedup vs baseline: 3.4736x; 1.0439x over previous
//
#include <hip/hip_runtime.h>
#include <cstdint>

// WealthRNN v15: v13 + (a) 4-bank 2-phase-ahead LDS prefetch in wave0,
// (b) batch = 8 groups per barrier (33 barriers), (c) wave1 DMA lead = 3
// batches (ring 32 slots), so every counted wait targets an op >=2 phases/
// batches old. All vmcnt/lgkmcnt constants hand-derived (tables inline).

#define S_LEN 1024
#define B_LEN 16384
#define GSTEP ((size_t)4 * B_LEN)

typedef uint32_t u32x4 __attribute__((ext_vector_type(4)));
typedef float    f32x4 __attribute__((ext_vector_type(4)));
typedef float    f32x2 __attribute__((ext_vector_type(2)));

__device__ __forceinline__ u32x4 make_srsrc(const void* p) {
    u32x4 r;
    uint64_t a = (uint64_t)p;
    r.x = (uint32_t)a;
    r.y = (uint32_t)(a >> 32);
    r.z = 0xFFFFFFFFu;
    r.w = 0x00020000u;
    return r;
}

#define SBAR0 __builtin_amdgcn_sched_barrier(0)
#define WAITV(N) do { asm volatile("s_waitcnt vmcnt(%0)" :: "n"(N)); SBAR0; } while (0)
#define LGKMN(N) do { asm volatile("s_waitcnt lgkmcnt(%0)" :: "n"(N)); SBAR0; } while (0)

__device__ __forceinline__ void dma16(const float* g, float* l) {
    __builtin_amdgcn_global_load_lds(
        (const __attribute__((address_space(1))) void*)g,
        (__attribute__((address_space(3))) void*)l, 16, 0, 0);
}

// exact step (tail only)
__device__ __forceinline__ float step_fn(float h, float x, float r,
                                         float win, float wh,
                                         float c1, float c2, float c3,
                                         float wf1, float wf2) {
    float inv   = __builtin_amdgcn_rcpf(fmaf(h, r, 1.0f));
    float h_adj = fmaf(h, r, h) * inv;
    float ingate = fmaf(wh, h_adj, fmaf(x, win, c1));
    float t  = fmaxf(ingate, 0.0f);
    float g2 = fmaf(wf1, t, c2);
    float t2 = fmaxf(g2, 0.0f);
    return fmaf(wf2, t2, c3);
}

// v8/v13 verified re-rooted chain (absmax 0.0 in R12).
struct Consts { float winwf1, whwf1, c1wf1c2, c2p, wf2, c3; };

template<bool POS>
__device__ __forceinline__ void step_fast(float& st, float& hv,
                                          float x, float r, const Consts& C) {
    float A1 = C.wf2 * r;
    float B1 = C.c3 * r;
    float w  = fmaf(C.whwf1, r, C.whwf1);
    float A2 = C.wf2 * w;
    float B2 = C.c3 * w;
    float KK = fmaf(x, C.winwf1, C.c1wf1c2);
    float u  = fmaf(A1, st, B1);
    float M  = fmaf(A2, st, B2);
    float q  = fmaf(u, u, 1.0f);
    float om = 1.0f - u;
    float p  = om * q;
    float Aa = fmaf(M, p, KK);
    if (POS) st = fmaxf(Aa, C.c2p);
    else     st = fminf(fmaxf(Aa, 0.0f), C.c2p);
    hv = fmaf(C.wf2, st, C.c3);
}

template<bool POS>
__device__ __forceinline__ void step_first(float& st, float& hv,
                                           float x, float r, float h0,
                                           const Consts& C) {
    float w  = fmaf(C.whwf1, r, C.whwf1);
    float KK = fmaf(x, C.winwf1, C.c1wf1c2);
    float u  = h0 * r;
    float M  = w * h0;
    float q  = fmaf(u, u, 1.0f);
    float om = 1.0f - u;
    float p  = om * q;
    float Aa = fmaf(M, p, KK);
    if (POS) st = fmaxf(Aa, C.c2p);
    else     st = fminf(fmaxf(Aa, 0.0f), C.c2p);
    hv = fmaf(C.wf2, st, C.c3);
}

struct Bank { f32x2 x01, x23, r01, r23; };

// ring: 32 slots x 512 floats {x[4][64], r[4][64]}
#define RDG(g_, BK) do { \
    uint32_t ax_ = rbase + (uint32_t)(((g_) & 31) * 2048); \
    uint32_t ar_ = ax_ + 1024u; \
    asm volatile("ds_read2_b32 %0, %1 offset0:0 offset1:64"    : "=v"((BK).x01) : "v"(ax_)); \
    asm volatile("ds_read2_b32 %0, %1 offset0:128 offset1:192" : "=v"((BK).x23) : "v"(ax_)); \
    asm volatile("ds_read2_b32 %0, %1 offset0:0 offset1:64"    : "=v"((BK).r01) : "v"(ar_)); \
    asm volatile("ds_read2_b32 %0, %1 offset0:128 offset1:192" : "=v"((BK).r23) : "v"(ar_)); \
} while (0)

#define STEPS4B(BK) do { \
    step_fast<POS>(st, hv0, (BK).x01.x, (BK).r01.x, C); \
    step_fast<POS>(st, hv1, (BK).x01.y, (BK).r01.y, C); \
    step_fast<POS>(st, hv2, (BK).x23.x, (BK).r23.x, C); \
    step_fast<POS>(st, hv3, (BK).x23.y, (BK).r23.y, C); \
} while (0)

#define WRG(WA_) do { \
    asm volatile("ds_write2_b32 %0, %1, %2 offset0:0 offset1:64"    :: "v"(WA_), "v"(hv0), "v"(hv1)); \
    asm volatile("ds_write2_b32 %0, %1, %2 offset0:128 offset1:192" :: "v"(WA_), "v"(hv2), "v"(hv3)); \
} while (0)

// standard phase: read 2 ahead, counted lgkm, compute, write.
// lgkm N: ops after r(g_cur) = 12 normally; 10 if g_cur%8==1 (its read was
// issued at prev phase-7 BOTTOM, only 10 DS ops follow it).
#define PHASE(gr_, BKR, LGN_, BKC, WOFF_) do { \
    RDG(gr_, BKR); \
    LGKMN(LGN_); \
    STEPS4B(BKC); \
    { uint32_t wa_ = wb + (WOFF_); WRG(wa_); } \
} while (0)

template<bool POS>
__device__ __forceinline__ void wave0_impl(
    const float* inputs, const float* returns,
    float pi_bar, float win, float wh, float bh, float wf1, float wf2,
    float* out, int b0, int lane, float* ringp, float* outbp)
{
    const int b = b0 + lane;
    const float c1 = bh - pi_bar;
    const float c2 = 2.0f * bh;
    const float c3 = pi_bar + bh;
    Consts C;
    C.winwf1  = win * wf1;
    C.whwf1   = wh * wf1;
    C.c1wf1c2 = fmaf(c1, wf1, c2);
    C.c2p     = fmaxf(c2, 0.0f);
    C.wf2     = wf2;
    C.c3      = c3;

    const float h0v = inputs[b];
    out[b] = h0v;                               // row 0

    const uint32_t rbase = (uint32_t)(uintptr_t)ringp + (uint32_t)lane * 4u;
    const uint32_t wbase = (uint32_t)(uintptr_t)outbp + (uint32_t)lane * 4u;

    asm volatile("" ::: "memory");
    __builtin_amdgcn_s_barrier();               // #0 (ring thru group 9 ready)

    Bank B0, B1, B2, B3;
    float st = 0.0f, hv0, hv1, hv2, hv3;

    RDG(0, B0);
    RDG(1, B1);
    LGKMN(0);

    // batches 0..30 (8 groups each); phase p computes bank p%4, reads ->(p+2)%4
    for (int bt = 0; bt < 31; ++bt) {
        const int g0 = 8 * bt;
        const uint32_t wb = wbase + (uint32_t)((bt & 1) << 13);
        // phase 0 (group g0, bank B0; read g0+2 -> B2)
        RDG(g0 + 2, B2);
        LGKMN(12);
        if (bt == 0) { step_first<POS>(st, hv0, B0.x01.x, B0.r01.x, h0v, C); }
        else         { step_fast<POS>(st, hv0, B0.x01.x, B0.r01.x, C); }
        step_fast<POS>(st, hv1, B0.x01.y, B0.r01.y, C);
        step_fast<POS>(st, hv2, B0.x23.x, B0.r23.x, C);
        step_fast<POS>(st, hv3, B0.x23.y, B0.r23.y, C);
        { uint32_t wa_ = wb; WRG(wa_); }
        PHASE(g0 + 3, B3, 10, B1, 1024);
        PHASE(g0 + 4, B0, 12, B2, 2048);
        PHASE(g0 + 5, B1, 12, B3, 3072);
        PHASE(g0 + 6, B2, 12, B0, 4096);
        PHASE(g0 + 7, B3, 12, B1, 5120);
        PHASE(g0 + 8, B0, 12, B2, 6144);
        // phase 7 (group g0+7, bank B3): write first, then bottom-read g0+9
        LGKMN(8);
        STEPS4B(B3);
        { uint32_t wa_ = wb + 7168u; WRG(wa_); }
        RDG(g0 + 9, B1);
        LGKMN(4);                   // all writes drained; 4 reads float
        __builtin_amdgcn_s_barrier();
    }

    // batch 31: groups 248..254 (7 phases), bank parity odd -> wb +8192
    {
        const uint32_t wb = wbase + 8192u;
        PHASE(250, B2, 12, B0, 0);
        PHASE(251, B3, 10, B1, 1024);
        PHASE(252, B0, 12, B2, 2048);
        PHASE(253, B1, 12, B3, 3072);
        PHASE(254, B2, 12, B0, 4096);
        PHASE(254, B3, 12, B1, 5120);   // clamped read (discard into B3)
        LGKMN(8);
        STEPS4B(B2);                     // group 254: steps 1017..1020
        { uint32_t wa_ = wb + 6144u; WRG(wa_); }
        LGKMN(0);
        __builtin_amdgcn_s_barrier();    // #32
    }

    asm volatile("" ::: "memory");

    // tail steps 1021..1023 + hT
    float h = hv3;                       // h_1020
#pragma unroll
    for (int s = 1021; s < S_LEN; ++s) {
        const float x = inputs[(size_t)s * B_LEN + b];
        const float r = returns[(size_t)(s - 1) * B_LEN + b];
        h = step_fn(h, x, r, win, wh, c1, c2, c3, wf1, wf2);
        out[(size_t)s * B_LEN + b] = h;
    }
    out[(size_t)S_LEN * B_LEN + b] = h;
}

// ---------------- wave1 ----------------
#define DMA_GROUP() do { \
    float* lb_ = &ringf[(size_t)(dmag & 31) * 512]; \
    dma16(gxw, lb_); dma16(grw, lb_ + 256); \
    gxw += GSTEP; grw += GSTEP; ++dmag; \
} while (0)

#define WDR8(LOFF_, O0,O1,O2,O3,O4,O5,O6,O7) do { \
    uint32_t a_ = oa + (LOFF_); \
    asm volatile("ds_read_b128 %0, %1 offset:0"    : "=v"(O0) : "v"(a_)); \
    asm volatile("ds_read_b128 %0, %1 offset:1024" : "=v"(O1) : "v"(a_)); \
    asm volatile("ds_read_b128 %0, %1 offset:2048" : "=v"(O2) : "v"(a_)); \
    asm volatile("ds_read_b128 %0, %1 offset:3072" : "=v"(O3) : "v"(a_)); \
    asm volatile("ds_read_b128 %0, %1 offset:4096" : "=v"(O4) : "v"(a_)); \
    asm volatile("ds_read_b128 %0, %1 offset:5120" : "=v"(O5) : "v"(a_)); \
    asm volatile("ds_read_b128 %0, %1 offset:6144" : "=v"(O6) : "v"(a_)); \
    asm volatile("ds_read_b128 %0, %1 offset:7168" : "=v"(O7) : "v"(a_)); \
} while (0)

#define BST(O_) do { \
    asm volatile("buffer_store_dwordx4 %0, %1, %2, %3 offen" \
                 :: "v"(O_), "v"(vo), "s"(ro), "s"(so_)); \
    so_ += (4u << 16); \
} while (0)

// one wave1 interval k (k>=1): barrier #k, DMA batch k+3, pre-wait, read
// outb bank (k-1)&1, store rows 32(k-1)+1.., end-wait.
// N tables (hand-derived, in-order retirement):
//   pre:  k=1..27:40, 28:38, 29:22, 30:8, 31:8
//   end:  k=1..27:36, 28:34, 29:18, 30:16, 31:skip
#define W1_ITER(k_, LOFF_, NDMA_, PREN_, ENDN_, DOEND_, O0,O1,O2,O3,O4,O5,O6,O7) do { \
    __builtin_amdgcn_s_barrier(); \
    for (int gi_ = 0; gi_ < (NDMA_); ++gi_) { DMA_GROUP(); } \
    asm volatile("s_waitcnt vmcnt(%0)" :: "n"(PREN_)); SBAR0; \
    asm volatile("" :: "v"(O0),"v"(O1),"v"(O2),"v"(O3),"v"(O4),"v"(O5),"v"(O6),"v"(O7)); \
    WDR8(LOFF_, O0,O1,O2,O3,O4,O5,O6,O7); \
    LGKMN(0); \
    { uint32_t so_ = ((uint32_t)(32 * ((k_) - 1) + 1)) << 16; \
      BST(O0); BST(O1); BST(O2); BST(O3); BST(O4); BST(O5); BST(O6); BST(O7); } \
    if (DOEND_) { asm volatile("s_waitcnt vmcnt(%0)" :: "n"(ENDN_)); SBAR0; } \
} while (0)

__global__ __launch_bounds__(128) void wealth_rnn_kernel(
    const float* __restrict__ inputs,    // [S, B]
    const float* __restrict__ returns,   // [S-1, B]
    const float* __restrict__ target,
    const float* __restrict__ w_in_p,
    const float* __restrict__ w_h_p,
    const float* __restrict__ b_h_p,
    const float* __restrict__ w_fc1_p,
    const float* __restrict__ w_fc2_p,
    float* __restrict__ out)             // [S*B] then [B] hT
{
    __shared__ float ringf[32 * 512];    // 64 KiB input ring (32 groups)
    __shared__ float outbf[2 * 8 * 256]; // 16 KiB output (2 banks x 8 groups)

    const int tid  = threadIdx.x;
    const int lane = tid & 63;
    const int wid  = tid >> 6;
    const int b0   = blockIdx.x * 64;

    if (wid == 0) {
        const float pi_bar = target[0];
        const float win = w_in_p[0];
        const float wh  = w_h_p[0];
        const float bh  = b_h_p[0];
        const float wf1 = w_fc1_p[0];
        const float wf2 = w_fc2_p[0];
        if (wf1 >= 0.0f)
            wave0_impl<true >(inputs, returns, pi_bar, win, wh, bh, wf1, wf2,
                              out, b0, lane, &ringf[0], &outbf[0]);
        else
            wave0_impl<false>(inputs, returns, pi_bar, win, wh, bh, wf1, wf2,
                              out, b0, lane, &ringf[0], &outbf[0]);
    } else {
        const int j = lane;
        u32x4 ro = make_srsrc(out);
        const uint32_t vo = (uint32_t)((((j >> 4) * B_LEN) + b0 + (j & 15) * 4) * 4);
        const uint32_t oa = (uint32_t)(uintptr_t)&outbf[0]
                            + (uint32_t)((j >> 4) * 256 + (j & 15) * 16);

        const int lr = j >> 4;
        const int lc = (j & 15) * 4;
        const float* gxw = inputs  + (size_t)(1 + lr) * B_LEN + b0 + lc;
        const float* grw = returns + (size_t)lr       * B_LEN + b0 + lc;
        int dmag = 0;

        // prologue: DMA batches 0..2 (groups 0..23, 48 ops); need thru group 9:
        // ops after group 9 = groups 10..23 = 28 -> WAITV(28)
        for (int gi = 0; gi < 24; ++gi) { DMA_GROUP(); }
        WAITV(28);
        __builtin_amdgcn_s_barrier();     // #0

        // interval 0: DMA batch 3; end-wait thru group 17 (after: 12+16=28)
        for (int gi = 0; gi < 8; ++gi) { DMA_GROUP(); }
        WAITV(28);

        f32x4 o0={0,0,0,0},o1={0,0,0,0},o2={0,0,0,0},o3={0,0,0,0},
              o4={0,0,0,0},o5={0,0,0,0},o6={0,0,0,0},o7={0,0,0,0};
        f32x4 p0={0,0,0,0},p1={0,0,0,0},p2={0,0,0,0},p3={0,0,0,0},
              p4={0,0,0,0},p5={0,0,0,0},p6={0,0,0,0},p7={0,0,0,0};

        // k = 1..26 (13 pairs), steady constants
        for (int k2 = 0; k2 < 13; ++k2) {
            const int k = 1 + 2 * k2;
            W1_ITER(k,     0,    8, 40, 36, 1, o0,o1,o2,o3,o4,o5,o6,o7);
            W1_ITER(k + 1, 8192, 8, 40, 36, 1, p0,p1,p2,p3,p4,p5,p6,p7);
        }
        // tail iters
        W1_ITER(27, 0,    8, 40, 36, 1, o0,o1,o2,o3,o4,o5,o6,o7);
        W1_ITER(28, 8192, 7, 38, 34, 1, p0,p1,p2,p3,p4,p5,p6,p7);  // batch 31 = 7 groups
        W1_ITER(29, 0,    0, 22, 18, 1, o0,o1,o2,o3,o4,o5,o6,o7);
        W1_ITER(30, 8192, 0,  8, 16, 1, p0,p1,p2,p3,p4,p5,p6,p7);
        W1_ITER(31, 0,    0,  8,  0, 0, o0,o1,o2,o3,o4,o5,o6,o7);
        __builtin_amdgcn_s_barrier();     // #32

        // final: batch 31 (7 groups, rows 993..1020), outb bank 1
        WAITV(8);                          // protect p-bank (stored iter 30)
        asm volatile("" :: "v"(p0),"v"(p1),"v"(p2),"v"(p3),"v"(p4),"v"(p5),"v"(p6));
        {
            uint32_t a_ = oa + 8192u;
            asm volatile("ds_read_b128 %0, %1 offset:0"    : "=v"(p0) : "v"(a_));
            asm volatile("ds_read_b128 %0, %1 offset:1024" : "=v"(p1) : "v"(a_));
            asm volatile("ds_read_b128 %0, %1 offset:2048" : "=v"(p2) : "v"(a_));
            asm volatile("ds_read_b128 %0, %1 offset:3072" : "=v"(p3) : "v"(a_));
            asm volatile("ds_read_b128 %0, %1 offset:4096" : "=v"(p4) : "v"(a_));
            asm volatile("ds_read_b128 %0, %1 offset:5120" : "=v"(p5) : "v"(a_));
            asm volatile("ds_read_b128 %0, %1 offset:6144" : "=v"(p6) : "v"(a_));
        }
        LGKMN(0);
        {
            uint32_t so_ = ((uint32_t)993) << 16;
            BST(p0); BST(p1); BST(p2); BST(p3); BST(p4); BST(p5); BST(p6);
        }
    }
}

extern "C" void kernel_launch(void* const* d_in, const int* in_sizes, int n_in,
                              void* d_out, int out_size, void* d_ws, size_t ws_size,
                              hipStream_t stream) {
    const float* inputs  = (const float*)d_in[0];
    const float* returns = (const float*)d_in[1];
    const float* target  = (const float*)d_in[2];
    const float* w_in    = (const float*)d_in[3];
    const float* w_h     = (const float*)d_in[4];
    const float* b_h     = (const float*)d_in[5];
    const float* w_fc1   = (const float*)d_in[6];
    const float* w_fc2   = (const float*)d_in[7];
    float* out = (float*)d_out;

    dim3 grid(B_LEN / 64);
    dim3 block(128);
    hipLaunchKernelGGL(wealth_rnn_kernel, grid, block, 0, stream,
                       inputs, returns, target, w_in, w_h, b_h, w_fc1, w_fc2, out);
}